// Round 1
// 519.825 us; speedup vs baseline: 1.3955x; 1.3955x over previous
//
#include <hip/hip_runtime.h>

// ParallelTransportUnpool:
//   out[dst[e], 0, ch, :] = x[c, 0, ch, :]
//   out[dst[e], 1, ch, :] = x[c, 1, ch, :] * conj(connection[e])   (complex mul)
// where c = position of edge_src[e] in sorted unpool_nodes.
//
// V2: replace the per-wave 16-deep binary-search dependent-load chain with a
// precomputed inverse map in workspace (map[nodes[i]] = i), and use 1 edge per
// wave (64 lanes x 2 float4) for 2x per-lane MLP and half the lookups.
// edge_dst is a permutation -> every output row written exactly once (no zero-init).

__global__ __launch_bounds__(256) void PTU_build_map_kernel(
    const int* __restrict__ nodes,   // (n_coarse,) sorted, values in [0, n_fine)
    int*       __restrict__ map,     // (n_fine,) workspace
    int n_coarse)
{
    int i = blockIdx.x * 256 + threadIdx.x;
    if (i < n_coarse) map[nodes[i]] = i;
}

__global__ __launch_bounds__(256) void ParallelTransportUnpool_87582973100651_kernel(
    const float4* __restrict__ x,          // (N_COARSE, 2, 128, 2) = 128 float4/row
    const float2* __restrict__ conn,       // (N_FINE, 2)
    const int*    __restrict__ map,        // (N_FINE,) inverse map in workspace
    const int*    __restrict__ edge_src,   // (N_FINE,)
    const int*    __restrict__ edge_dst,   // (N_FINE,)
    float4*       __restrict__ out,        // (N_FINE, 2, 128, 2) = 128 float4/row
    int n_fine)
{
    // 4 edges per 256-thread block; one wave (64 lanes) per edge.
    // lane handles float4 slots {lane} (group 0) and {lane+64} (group 1).
    int wv = __builtin_amdgcn_readfirstlane(threadIdx.x >> 6);
    int e  = blockIdx.x * 4 + wv;
    if (e >= n_fine) return;
    int lane = threadIdx.x & 63;

    // Wave-uniform scalars -> SGPRs.
    int s = __builtin_amdgcn_readfirstlane(edge_src[e]);
    int d = __builtin_amdgcn_readfirstlane(edge_dst[e]);
    int c = __builtin_amdgcn_readfirstlane(map[s]);

    const float4* __restrict__ xr = x + (size_t)c * 128;
    float4 v0 = xr[lane];        // group 0 element (independent load #1)
    float4 v1 = xr[lane + 64];   // group 1 element (independent load #2)
    float2 b  = conn[e];         // wave-uniform broadcast

    // v1 *= conj(b):  (re,im) * (br, -bim)
    float br = b.x, bi = -b.y;
    float4 r;
    r.x = v1.x * br - v1.y * bi;
    r.y = v1.x * bi + v1.y * br;
    r.z = v1.z * br - v1.w * bi;
    r.w = v1.z * bi + v1.w * br;

    float4* __restrict__ orow = out + (size_t)d * 128;
    orow[lane]      = v0;
    orow[lane + 64] = r;
}

// Fallback (workspace too small): original binary-search version.
__global__ __launch_bounds__(256) void PTU_bsearch_kernel(
    const float4* __restrict__ x,
    const float2* __restrict__ conn,
    const int*    __restrict__ nodes,
    const int*    __restrict__ edge_src,
    const int*    __restrict__ edge_dst,
    float4*       __restrict__ out,
    int n_fine, int n_coarse)
{
    int e = blockIdx.x * 2 + (threadIdx.x >> 7);
    if (e >= n_fine) return;
    int lane = threadIdx.x & 127;

    int s = edge_src[e];
    int d = edge_dst[e];

    int lo = 0, hi = n_coarse - 1;
    while (lo < hi) {
        int mid = (lo + hi) >> 1;
        if (nodes[mid] < s) lo = mid + 1; else hi = mid;
    }
    int c = lo;

    float4 v = x[(size_t)c * 128 + lane];
    if (lane >= 64) {
        float2 b = conn[e];
        float br = b.x, bi = -b.y;
        float4 r;
        r.x = v.x * br - v.y * bi;
        r.y = v.x * bi + v.y * br;
        r.z = v.z * br - v.w * bi;
        r.w = v.z * bi + v.w * br;
        v = r;
    }
    out[(size_t)d * 128 + lane] = v;
}

extern "C" void kernel_launch(void* const* d_in, const int* in_sizes, int n_in,
                              void* d_out, int out_size, void* d_ws, size_t ws_size,
                              hipStream_t stream) {
    const float4* x     = (const float4*)d_in[0];
    const float2* conn  = (const float2*)d_in[1];
    const int*    nodes = (const int*)d_in[2];
    const int*    edges = (const int*)d_in[3];   // (2, N_FINE): row0 = src, row1 = dst

    const int n_coarse = in_sizes[2];
    const int n_fine   = in_sizes[3] / 2;

    const int* edge_src = edges;
    const int* edge_dst = edges + n_fine;

    float4* out = (float4*)d_out;

    if (ws_size >= (size_t)n_fine * sizeof(int)) {
        int* map = (int*)d_ws;
        int mblocks = (n_coarse + 255) / 256;
        PTU_build_map_kernel<<<mblocks, 256, 0, stream>>>(nodes, map, n_coarse);

        int blocks = (n_fine + 3) / 4;   // 4 edges per block, 1 wave per edge
        ParallelTransportUnpool_87582973100651_kernel<<<blocks, 256, 0, stream>>>(
            x, conn, map, edge_src, edge_dst, out, n_fine);
    } else {
        int blocks = (n_fine + 1) / 2;
        PTU_bsearch_kernel<<<blocks, 256, 0, stream>>>(
            x, conn, nodes, edge_src, edge_dst, out, n_fine, n_coarse);
    }
}

// Round 3
// 503.667 us; speedup vs baseline: 1.4403x; 1.0321x over previous
//
#include <hip/hip_runtime.h>

// ParallelTransportUnpool:
//   out[dst[e], 0, ch, :] = x[c, 0, ch, :]
//   out[dst[e], 1, ch, :] = x[c, 1, ch, :] * conj(connection[e])
// where c = position of edge_src[e] in sorted unpool_nodes.
//
// V3b: edge_dst is a permutation -> invert it so the 410 MB output is written as
// a SEQUENTIAL stream (row r in order) instead of a random 2 KB scatter.
//   setup1: map[nodes[i]] = i
//   setup2: rowinfo[edge_dst[e]] = {c=map[edge_src[e]], conn[e].x, conn[e].y}
//   main:   wave r: read rowinfo[r] (sequential), gather x row c (L3-resident),
//           write out row r (sequential, nontemporal -> don't evict x from L2/L3).
// Fix vs V3: __builtin_nontemporal_store needs a clang vector type, not HIP float4.

typedef float v4f __attribute__((ext_vector_type(4)));

__global__ __launch_bounds__(256) void PTU_build_map_kernel(
    const int* __restrict__ nodes,   // (n_coarse,) sorted, values in [0, n_fine)
    int*       __restrict__ map,     // (n_fine,)
    int n_coarse)
{
    int i = blockIdx.x * 256 + threadIdx.x;
    if (i < n_coarse) map[nodes[i]] = i;
}

__global__ __launch_bounds__(256) void PTU_build_rowinfo_kernel(
    const int*    __restrict__ map,        // (n_fine,)
    const float2* __restrict__ conn,       // (n_fine,)
    const int*    __restrict__ edge_src,   // (n_fine,)
    const int*    __restrict__ edge_dst,   // (n_fine,)
    float4*       __restrict__ rowinfo,    // (n_fine,) {c_as_float, br, bi, 0}
    int n_fine)
{
    int e = blockIdx.x * 256 + threadIdx.x;
    if (e >= n_fine) return;
    int s = edge_src[e];
    int d = edge_dst[e];
    int c = map[s];
    float2 b = conn[e];
    rowinfo[d] = make_float4(__int_as_float(c), b.x, b.y, 0.0f);
}

__global__ __launch_bounds__(256) void ParallelTransportUnpool_87582973100651_kernel(
    const float4* __restrict__ x,          // (N_COARSE, 2, 128, 2) = 128 float4/row
    const float4* __restrict__ rowinfo,    // (N_FINE,)
    float4*       __restrict__ out,        // (N_FINE, 2, 128, 2) = 128 float4/row
    int n_fine)
{
    // 4 output rows per 256-thread block; one wave (64 lanes) per row.
    // Rows are processed IN ORDER -> out writes are a sequential stream.
    int wv = threadIdx.x >> 6;
    int r  = blockIdx.x * 4 + wv;
    if (r >= n_fine) return;
    int lane = threadIdx.x & 63;

    float4 info = rowinfo[r];                       // wave-uniform 16B broadcast
    int   c  = __builtin_amdgcn_readfirstlane(__float_as_int(info.x));
    float br = info.y;
    float bi = -info.z;                             // conj

    const float4* __restrict__ xr = x + (size_t)c * 128;
    float4 v0 = xr[lane];        // group 0 (independent load #1)
    float4 v1 = xr[lane + 64];   // group 1 (independent load #2)

    float4 t;
    t.x = v1.x * br - v1.y * bi;
    t.y = v1.x * bi + v1.y * br;
    t.z = v1.z * br - v1.w * bi;
    t.w = v1.z * bi + v1.w * br;

    float4* orow = out + (size_t)r * 128;
    // Nontemporal streaming stores (write-once data; keep x resident in L2/L3).
    v4f nv0 = { v0.x, v0.y, v0.z, v0.w };
    v4f nv1 = { t.x,  t.y,  t.z,  t.w  };
    __builtin_nontemporal_store(nv0, reinterpret_cast<v4f*>(&orow[lane]));
    __builtin_nontemporal_store(nv1, reinterpret_cast<v4f*>(&orow[lane + 64]));
}

// Fallback path (workspace smaller than rowinfo+map): V2 map-gather version.
__global__ __launch_bounds__(256) void PTU_map_scatter_kernel(
    const float4* __restrict__ x,
    const float2* __restrict__ conn,
    const int*    __restrict__ map,
    const int*    __restrict__ edge_src,
    const int*    __restrict__ edge_dst,
    float4*       __restrict__ out,
    int n_fine)
{
    int wv = __builtin_amdgcn_readfirstlane(threadIdx.x >> 6);
    int e  = blockIdx.x * 4 + wv;
    if (e >= n_fine) return;
    int lane = threadIdx.x & 63;

    int s = __builtin_amdgcn_readfirstlane(edge_src[e]);
    int d = __builtin_amdgcn_readfirstlane(edge_dst[e]);
    int c = __builtin_amdgcn_readfirstlane(map[s]);

    const float4* __restrict__ xr = x + (size_t)c * 128;
    float4 v0 = xr[lane];
    float4 v1 = xr[lane + 64];
    float2 b  = conn[e];

    float br = b.x, bi = -b.y;
    float4 t;
    t.x = v1.x * br - v1.y * bi;
    t.y = v1.x * bi + v1.y * br;
    t.z = v1.z * br - v1.w * bi;
    t.w = v1.z * bi + v1.w * br;

    float4* orow = out + (size_t)d * 128;
    orow[lane]      = v0;
    orow[lane + 64] = t;
}

// Last-resort fallback: original binary-search version (no workspace).
__global__ __launch_bounds__(256) void PTU_bsearch_kernel(
    const float4* __restrict__ x,
    const float2* __restrict__ conn,
    const int*    __restrict__ nodes,
    const int*    __restrict__ edge_src,
    const int*    __restrict__ edge_dst,
    float4*       __restrict__ out,
    int n_fine, int n_coarse)
{
    int e = blockIdx.x * 2 + (threadIdx.x >> 7);
    if (e >= n_fine) return;
    int lane = threadIdx.x & 127;

    int s = edge_src[e];
    int d = edge_dst[e];

    int lo = 0, hi = n_coarse - 1;
    while (lo < hi) {
        int mid = (lo + hi) >> 1;
        if (nodes[mid] < s) lo = mid + 1; else hi = mid;
    }
    int c = lo;

    float4 v = x[(size_t)c * 128 + lane];
    if (lane >= 64) {
        float2 b = conn[e];
        float br = b.x, bi = -b.y;
        float4 t;
        t.x = v.x * br - v.y * bi;
        t.y = v.x * bi + v.y * br;
        t.z = v.z * br - v.w * bi;
        t.w = v.z * bi + v.w * br;
        v = t;
    }
    out[(size_t)d * 128 + lane] = v;
}

extern "C" void kernel_launch(void* const* d_in, const int* in_sizes, int n_in,
                              void* d_out, int out_size, void* d_ws, size_t ws_size,
                              hipStream_t stream) {
    const float4* x     = (const float4*)d_in[0];
    const float2* conn  = (const float2*)d_in[1];
    const int*    nodes = (const int*)d_in[2];
    const int*    edges = (const int*)d_in[3];   // (2, N_FINE): row0 = src, row1 = dst

    const int n_coarse = in_sizes[2];
    const int n_fine   = in_sizes[3] / 2;

    const int* edge_src = edges;
    const int* edge_dst = edges + n_fine;

    float4* out = (float4*)d_out;

    const size_t need_full = (size_t)n_fine * sizeof(float4) + (size_t)n_fine * sizeof(int);
    const size_t need_map  = (size_t)n_fine * sizeof(int);

    if (ws_size >= need_full) {
        float4* rowinfo = (float4*)d_ws;                 // 16B-aligned workspace base
        int*    map     = (int*)(rowinfo + n_fine);

        int mblocks = (n_coarse + 255) / 256;
        PTU_build_map_kernel<<<mblocks, 256, 0, stream>>>(nodes, map, n_coarse);

        int eblocks = (n_fine + 255) / 256;
        PTU_build_rowinfo_kernel<<<eblocks, 256, 0, stream>>>(
            map, conn, edge_src, edge_dst, rowinfo, n_fine);

        int blocks = (n_fine + 3) / 4;   // 4 rows per block, 1 wave per row
        ParallelTransportUnpool_87582973100651_kernel<<<blocks, 256, 0, stream>>>(
            x, rowinfo, out, n_fine);
    } else if (ws_size >= need_map) {
        int* map = (int*)d_ws;
        int mblocks = (n_coarse + 255) / 256;
        PTU_build_map_kernel<<<mblocks, 256, 0, stream>>>(nodes, map, n_coarse);

        int blocks = (n_fine + 3) / 4;
        PTU_map_scatter_kernel<<<blocks, 256, 0, stream>>>(
            x, conn, map, edge_src, edge_dst, out, n_fine);
    } else {
        int blocks = (n_fine + 1) / 2;
        PTU_bsearch_kernel<<<blocks, 256, 0, stream>>>(
            x, conn, nodes, edge_src, edge_dst, out, n_fine, n_coarse);
    }
}